// Round 18
// baseline (259.631 us; speedup 1.0000x reference)
//
#include <hip/hip_runtime.h>
#include <cstdint>
#include <cstddef>
#include <cmath>

typedef __attribute__((ext_vector_type(4))) float f32x4;
typedef __attribute__((ext_vector_type(8))) short bf16x8;

typedef const __attribute__((address_space(1))) void* gas_ptr;
typedef __attribute__((address_space(3))) void* las_ptr;

// compiler-native bf16 convert (RNE)
static __device__ __forceinline__ short f2bf(float f) {
    __bf16 h = (__bf16)f;
    return __builtin_bit_cast(short, h);
}

constexpr int MP = 25088;   // 64 * 392 batch-padded rows

// ---------------- merged fp32 -> bf16 conversion (one launch) ----------------
__global__ void cvt_all(const float* __restrict__ x,  const float* __restrict__ qw,
                        const float* __restrict__ pw,
                        short* __restrict__ xb, short* __restrict__ qwb,
                        short* __restrict__ pwb)
{
    constexpr int NX = MP * 768 / 4;
    constexpr int NQ = 2304 * 768 / 4;
    constexpr int NP = 768 * 768 / 4;
    constexpr int NT = NX + NQ + NP;
    int i = blockIdx.x * blockDim.x + threadIdx.x;
    const int stride = gridDim.x * blockDim.x;
    for (; i < NT; i += stride) {
        if (i < NX) {
            const int flat = i * 4;
            const int mp  = flat / 768;
            const int col = flat - mp * 768;
            const int b   = mp / 392;
            const int nn  = mp - b * 392;
            short4 o;
            if (nn < 388) {
                const float4 v = *reinterpret_cast<const float4*>(
                    x + ((size_t)(b * 388 + nn) * 768 + col));
                o.x = f2bf(v.x); o.y = f2bf(v.y); o.z = f2bf(v.z); o.w = f2bf(v.w);
            } else {
                o.x = 0; o.y = 0; o.z = 0; o.w = 0;
            }
            reinterpret_cast<short4*>(xb)[i] = o;
        } else if (i < NX + NQ) {
            const int j = i - NX;
            const float4 v = reinterpret_cast<const float4*>(qw)[j];
            short4 o;
            o.x = f2bf(v.x); o.y = f2bf(v.y); o.z = f2bf(v.z); o.w = f2bf(v.w);
            reinterpret_cast<short4*>(qwb)[j] = o;
        } else {
            const int j = i - NX - NQ;
            const float4 v = reinterpret_cast<const float4*>(pw)[j];
            short4 o;
            o.x = f2bf(v.x); o.y = f2bf(v.y); o.z = f2bf(v.z); o.w = f2bf(v.w);
            reinterpret_cast<short4*>(pwb)[j] = o;
        }
    }
}

// ---------------- QKV GEMM: A in registers, B in LDS ----------------
// 128x128 tile, BK=64, 4 waves = 4 m-slices (wave tile 32 rows x 128 cols).
// A is wave-private -> loaded global->reg (4 b128/lane/iter, reg-dbuf);
// LDS holds B ONLY: 32KB dbuf -> 3 blocks/CU (launch_bounds cap), per-iter
// LDS traffic 80KB vs 96KB. Same counted-vmcnt(8) 2-barrier skeleton as r14
// (4 A-glb + 4 B-DMA = 8 ops/iter). Supertile G=14 keeps A rows L2-hot.
__global__ __launch_bounds__(256, 3) void gemm_qkv_areg(
    const short* __restrict__ A, const short* __restrict__ Bw,
    const float* __restrict__ bias,
    short* __restrict__ qk, short* __restrict__ vT)
{
    constexpr int K = 768;
    __shared__ __align__(16) short ldsB[2][128 * 64];   // 32KB

    const int tid  = threadIdx.x;
    const int lane = tid & 63;
    const int wid  = tid >> 6;
    const int lrow = lane & 15;
    const int lgrp = lane >> 4;

    const int nwg = gridDim.x;
    const int q8  = nwg >> 3, r8 = nwg & 7;
    const int xcd = blockIdx.x & 7, bidx = blockIdx.x >> 3;
    const int wgid = (xcd < r8 ? xcd * (q8 + 1) : r8 * (q8 + 1) + (xcd - r8) * q8) + bidx;

    constexpr int G = 14, SG = G * 18;
    const int mg = wgid / SG;
    const int r_ = wgid - mg * SG;
    const int n_ = r_ / G;
    const int mi = r_ - n_ * G;
    const int m0 = (mg * G + mi) * 128;
    const int n0 = n_ * 128;

    f32x4 acc[2][8];
    #pragma unroll
    for (int i = 0; i < 2; ++i)
        #pragma unroll
        for (int j = 0; j < 8; ++j)
            acc[i][j] = f32x4{0.f, 0.f, 0.f, 0.f};

    // wave's A rows: m0 + wid*32 + i*16 + lrow (i in 0..1); frag layout fixed
    const short* arow0 = A + (size_t)(m0 + wid * 32 + lrow) * K;
    const short* arow1 = arow0 + (size_t)16 * K;

    auto loadA = [&](int kt, bf16x8 (&dst)[2][2]) {
        #pragma unroll
        for (int ks = 0; ks < 2; ++ks) {
            dst[0][ks] = *reinterpret_cast<const bf16x8*>(arow0 + kt * 64 + ks * 32 + lgrp * 8);
            dst[1][ks] = *reinterpret_cast<const bf16x8*>(arow1 + kt * 64 + ks * 32 + lgrp * 8);
        }
    };
    auto stageB = [&](int kt, int buf) {
        #pragma unroll
        for (int it = 0; it < 4; ++it) {
            const int c   = it * 256 + tid;                  // 0..1023
            const int row = c >> 3;
            const int scb = ((c & 7) * 16) ^ ((row & 7) << 4);
            const short* gb = Bw + (size_t)(n0 + row) * K + kt * 64 + (scb >> 1);
            __builtin_amdgcn_global_load_lds((gas_ptr)gb, (las_ptr)((char*)&ldsB[buf][0] + c * 16), 16, 0, 0);
        }
    };
    auto compute = [&](int buf, const bf16x8 (&af)[2][2]) {
        #pragma unroll
        for (int ks = 0; ks < 2; ++ks) {
            bf16x8 bfv[8];
            #pragma unroll
            for (int j = 0; j < 8; ++j) {
                const int r   = j * 16 + lrow;
                const int byt = r * 128 + ((ks * 64 + lgrp * 16) ^ ((r & 7) << 4));
                bfv[j] = *reinterpret_cast<const bf16x8*>((const char*)&ldsB[buf][0] + byt);
            }
            #pragma unroll
            for (int i = 0; i < 2; ++i)
                #pragma unroll
                for (int j = 0; j < 8; ++j)
                    acc[i][j] = __builtin_amdgcn_mfma_f32_16x16x32_bf16(af[i][ks], bfv[j], acc[i][j], 0, 0, 0);
        }
    };

    bf16x8 afX[2][2], afY[2][2];

    // prologue: tile 0 (A->afX regs, B->LDS buf0)
    loadA(0, afX);
    stageB(0, 0);
    asm volatile("s_waitcnt vmcnt(0)" ::: "memory");
    __builtin_amdgcn_s_barrier();
    __builtin_amdgcn_sched_barrier(0);

    #pragma unroll 1
    for (int u = 0; u < 6; ++u) {
        // ---- even iter kt=2u: compute(buf0, afX); prefetch 2u+1 -> (afY, buf1)
        loadA(2 * u + 1, afY);
        stageB(2 * u + 1, 1);
        __builtin_amdgcn_sched_barrier(0);
        asm volatile("s_waitcnt vmcnt(8)" ::: "memory");   // tile 2u fully landed
        __builtin_amdgcn_s_barrier();
        __builtin_amdgcn_sched_barrier(0);
        compute(0, afX);
        __builtin_amdgcn_sched_barrier(0);
        __builtin_amdgcn_s_barrier();

        // ---- odd iter kt=2u+1: compute(buf1, afY); prefetch 2u+2 -> (afX, buf0)
        const bool more = (2 * u + 2 < 12);
        if (more) {
            loadA(2 * u + 2, afX);
            stageB(2 * u + 2, 0);
        }
        __builtin_amdgcn_sched_barrier(0);
        if (more) asm volatile("s_waitcnt vmcnt(8)" ::: "memory");
        else      asm volatile("s_waitcnt vmcnt(0)" ::: "memory");
        __builtin_amdgcn_s_barrier();
        __builtin_amdgcn_sched_barrier(0);
        compute(1, afY);
        __builtin_amdgcn_sched_barrier(0);
        __builtin_amdgcn_s_barrier();
    }

    // ---------------- epilogue (wave tile 32 rows x 128 cols) ----------------
    const int mrow = m0 + wid * 32;
    if (n0 < 1536) {
        // q/k: coalesced bf16 store into qkb [MP][1536]
        #pragma unroll
        for (int j = 0; j < 8; ++j) {
            const int c  = n0 + j * 16 + lrow;
            const float sc = (c < 768) ? 0.18033688011116f : 1.0f;  // 0.125*log2(e) on q
            const float bv = bias[c];
            #pragma unroll
            for (int i = 0; i < 2; ++i) {
                #pragma unroll
                for (int r = 0; r < 4; ++r) {
                    const int m = mrow + i * 16 + lgrp * 4 + r;
                    qk[(size_t)m * 1536 + c] = f2bf((acc[i][j][r] + bv) * sc);
                }
            }
        }
    } else {
        // v: per-wave [128 colLocal][32 n] LDS transpose in the B pool (8KB/wave),
        // then coalesced 16B vT stores. One-shot; mild bank conflicts acceptable.
        const int hb = (n0 - 1536) >> 6;
        short* lw = &ldsB[0][0] + wid * 4096;
        #pragma unroll
        for (int j = 0; j < 8; ++j) {
            const int colLocal = j * 16 + lrow;
            const float bv = bias[n0 + colLocal];
            #pragma unroll
            for (int i = 0; i < 2; ++i)
                #pragma unroll
                for (int r = 0; r < 4; ++r) {
                    const int n = i * 16 + lgrp * 4 + r;
                    lw[colLocal * 32 + n] = f2bf(acc[i][j][r] + bv);
                }
        }
        asm volatile("s_waitcnt lgkmcnt(0)" ::: "memory");
        __builtin_amdgcn_sched_barrier(0);
        #pragma unroll
        for (int it = 0; it < 8; ++it) {
            const int colLocal = it * 16 + (lane >> 2);
            const int nloc     = (lane & 3) * 8;
            const bf16x8 val = *reinterpret_cast<const bf16x8*>(lw + colLocal * 32 + nloc);
            const int h = hb + (colLocal >> 6);
            const int d = colLocal & 63;
            const int mchunk = mrow + nloc;              // mult of 8; 392%8==0
            const int b  = mchunk / 392;
            const int nn = mchunk - b * 392;
            short* dst = vT + ((size_t)(b * 12 + h) * 64 + d) * 392 + nn;
            *reinterpret_cast<bf16x8*>(dst) = val;
        }
    }
}

// ---------------- proj GEMM (r14 engine, unchanged) ----------------
__global__ __launch_bounds__(256) void gemm_proj(
    const short* __restrict__ A, const short* __restrict__ Bw,
    const float* __restrict__ bias, float* __restrict__ fo, int NB)
{
    constexpr int K = 768;
    constexpr int KT = 12;
    __shared__ __align__(16) short ldsraw[2 * 128 * 64 * 2];
    short* ldsA = ldsraw;
    short* ldsB = ldsraw + 2 * 128 * 64;

    const int tid  = threadIdx.x;
    const int lane = tid & 63;
    const int wid  = tid >> 6;
    const int lrow = lane & 15;
    const int lgrp = lane >> 4;
    const int wr   = wid >> 1;
    const int wc   = wid & 1;

    const int nwg = gridDim.x;
    const int q8  = nwg >> 3, r8 = nwg & 7;
    const int xcd = blockIdx.x & 7, bidx = blockIdx.x >> 3;
    const int wgid = (xcd < r8 ? xcd * (q8 + 1) : r8 * (q8 + 1) + (xcd - r8) * q8) + bidx;
    const int m0 = (wgid / NB) * 128;
    const int n0 = (wgid % NB) * 128;

    f32x4 acc[4][4];
    #pragma unroll
    for (int i = 0; i < 4; ++i)
        #pragma unroll
        for (int j = 0; j < 4; ++j)
            acc[i][j] = f32x4{0.f, 0.f, 0.f, 0.f};

    auto stage = [&](int kt, int buf) {
        #pragma unroll
        for (int it = 0; it < 4; ++it) {
            const int c   = it * 256 + wid * 64 + lane;
            const int row = c >> 3;
            const int scb = ((c & 7) * 16) ^ ((row & 7) << 4);
            const short* ga = A  + (size_t)(m0 + row) * K + kt * 64 + (scb >> 1);
            const short* gb = Bw + (size_t)(n0 + row) * K + kt * 64 + (scb >> 1);
            __builtin_amdgcn_global_load_lds((gas_ptr)ga, (las_ptr)((char*)(ldsA + buf * 128 * 64) + c * 16), 16, 0, 0);
            __builtin_amdgcn_global_load_lds((gas_ptr)gb, (las_ptr)((char*)(ldsB + buf * 128 * 64) + c * 16), 16, 0, 0);
        }
    };

    stage(0, 0);

    for (int kt = 0; kt < KT; ++kt) {
        const int cur = kt & 1;
        if (kt + 1 < KT) {
            stage(kt + 1, cur ^ 1);
            asm volatile("s_waitcnt vmcnt(8)" ::: "memory");
        } else {
            asm volatile("s_waitcnt vmcnt(0)" ::: "memory");
        }
        __builtin_amdgcn_s_barrier();
        __builtin_amdgcn_sched_barrier(0);

        #pragma unroll
        for (int ks = 0; ks < 2; ++ks) {
            bf16x8 af[4], bfv[4];
            #pragma unroll
            for (int i = 0; i < 4; ++i) {
                const int r   = wr * 64 + i * 16 + lrow;
                const int byt = r * 128 + ((ks * 64 + lgrp * 16) ^ ((r & 7) << 4));
                af[i] = *reinterpret_cast<const bf16x8*>((const char*)(ldsA + cur * 128 * 64) + byt);
            }
            #pragma unroll
            for (int j = 0; j < 4; ++j) {
                const int r   = wc * 64 + j * 16 + lrow;
                const int byt = r * 128 + ((ks * 64 + lgrp * 16) ^ ((r & 7) << 4));
                bfv[j] = *reinterpret_cast<const bf16x8*>((const char*)(ldsB + cur * 128 * 64) + byt);
            }
            #pragma unroll
            for (int i = 0; i < 4; ++i)
                #pragma unroll
                for (int j = 0; j < 4; ++j)
                    acc[i][j] = __builtin_amdgcn_mfma_f32_16x16x32_bf16(af[i], bfv[j], acc[i][j], 0, 0, 0);
        }

        __builtin_amdgcn_sched_barrier(0);
        __builtin_amdgcn_s_barrier();
    }

    const int mb = m0 + wr * 64;
    const int nb = n0 + wc * 64;
    #pragma unroll
    for (int i = 0; i < 4; ++i) {
        #pragma unroll
        for (int r = 0; r < 4; ++r) {
            const int m = mb + i * 16 + lgrp * 4 + r;
            #pragma unroll
            for (int j = 0; j < 4; ++j) {
                const int c = nb + j * 16 + lrow;
                fo[(size_t)m * 768 + c] = acc[i][j][r] + bias[c];
            }
        }
    }
}

// ---------------- flash attention (r14, unchanged) ----------------
constexpr int PSTRB = 128;   // P row stride BYTES (64 keys)

static __device__ __forceinline__ void attn_chunk64(
    int kbeg, int k_len,
    const short* __restrict__ klds, const short* __restrict__ vlds,
    const bf16x8 (&qf)[2], char* __restrict__ my,
    int lrow, int lgrp,
    float& rs, f32x4 (&oacc)[4])
{
    f32x4 sacc[4];
    #pragma unroll
    for (int t = 0; t < 4; ++t) sacc[t] = f32x4{0.f, 0.f, 0.f, 0.f};

    #pragma unroll
    for (int t = 0; t < 4; ++t) {
        const int kl   = t * 16 + lrow;
        const int byt0 = kl * 128 + ((lgrp * 16) ^ ((kl & 7) << 4));
        const int byt1 = kl * 128 + ((64 + lgrp * 16) ^ ((kl & 7) << 4));
        const bf16x8 k0 = *reinterpret_cast<const bf16x8*>((const char*)klds + byt0);
        const bf16x8 k1 = *reinterpret_cast<const bf16x8*>((const char*)klds + byt1);
        // SWAPPED: A = K rows (keys), B = Q rows (q)
        sacc[t] = __builtin_amdgcn_mfma_f32_16x16x32_bf16(k0, qf[0], sacc[t], 0, 0, 0);
        sacc[t] = __builtin_amdgcn_mfma_f32_16x16x32_bf16(k1, qf[1], sacc[t], 0, 0, 0);
    }

    if (kbeg + 64 <= k_len) {          // uniform fast path: no key masking
        #pragma unroll
        for (int t = 0; t < 4; ++t) {
            short4 pk;
            #pragma unroll
            for (int r = 0; r < 4; ++r) {
                const float p = exp2f(sacc[t][r]);
                rs += p;
                ((short*)&pk)[r] = f2bf(p);
            }
            const int byt = lrow * PSTRB + ((t * 32 + lgrp * 8) ^ ((lrow & 7) << 4));
            *reinterpret_cast<short4*>(my + byt) = pk;
        }
    } else {
        #pragma unroll
        for (int t = 0; t < 4; ++t) {
            short4 pk;
            #pragma unroll
            for (int r = 0; r < 4; ++r) {
                const int key = kbeg + t * 16 + lgrp * 4 + r;   // row-indexed
                const float p = (key < k_len) ? exp2f(sacc[t][r]) : 0.f;
                rs += p;
                ((short*)&pk)[r] = f2bf(p);
            }
            const int byt = lrow * PSTRB + ((t * 32 + lgrp * 8) ^ ((lrow & 7) << 4));
            *reinterpret_cast<short4*>(my + byt) = pk;
        }
    }

    #pragma unroll
    for (int ks = 0; ks < 2; ++ks) {
        const bf16x8 pf = *reinterpret_cast<const bf16x8*>(
            my + lrow * PSTRB + ((ks * 64 + lgrp * 16) ^ ((lrow & 7) << 4)));
        #pragma unroll
        for (int dt = 0; dt < 4; ++dt) {
            const int d = dt * 16 + lrow;
            const bf16x8 vf = *reinterpret_cast<const bf16x8*>(
                (const char*)vlds + d * 128 + ((ks * 64 + lgrp * 16) ^ ((d & 7) << 4)));
            oacc[dt] = __builtin_amdgcn_mfma_f32_16x16x32_bf16(pf, vf, oacc[dt], 0, 0, 0);
        }
    }
}

// grid 5376 1-D; temporal-L2 map: 7 q-tiles of one bh consecutive on one XCD.
__global__ __launch_bounds__(256, 4) void attn_flash(
    const short* __restrict__ qkb, const short* __restrict__ vT,
    short* __restrict__ ao)
{
    __shared__ __align__(16) short klds[2][64 * 64];    // 16KB dbuf, swizzled
    __shared__ __align__(16) short vlds[2][64 * 64];    // 16KB dbuf, swizzled
    __shared__ __align__(16) char  plds[4][16 * PSTRB]; // 8KB, swizzled

    const int tid  = threadIdx.x;
    const int lane = tid & 63;
    const int wid  = tid >> 6;
    const int lrow = lane & 15;
    const int lgrp = lane >> 4;

    const int blk = blockIdx.x;
    const int xcd = blk & 7;
    const int i7  = blk >> 3;
    const int bh  = xcd * 96 + i7 / 7;
    const int bx  = i7 % 7;

    int q_start, qend, k_len, nch;
    if (bx < 2) { q_start = bx * 64;             qend = 128; k_len = 128; nch = 2; }
    else        { q_start = 128 + (bx - 2) * 64; qend = 388; k_len = 388; nch = 7; }

    const int q0 = q_start + wid * 16;

    const int b = bh / 12, h = bh - b * 12;
    const short* qbase = qkb + (size_t)b * 392 * 1536 + h * 64;
    const short* kbase = qbase + 768;
    const short* vbase = vT + (size_t)bh * 64 * 392;

    int qrow = q0 + lrow; if (qrow >= qend) qrow = qend - 1;
    bf16x8 qf[2];
    #pragma unroll
    for (int ks = 0; ks < 2; ++ks)
        qf[ks] = *reinterpret_cast<const bf16x8*>(qbase + (size_t)qrow * 1536 + ks * 32 + lgrp * 8);

    float rs = 0.f;
    f32x4 oacc[4];
    #pragma unroll
    for (int dt = 0; dt < 4; ++dt) oacc[dt] = f32x4{0.f, 0.f, 0.f, 0.f};

    char* my = &plds[wid][0];

    auto stage64 = [&](int ch, int buf) {
        const int kbeg = ch * 64;
        #pragma unroll
        for (int it = 0; it < 2; ++it) {
            const int c = it * 256 + tid;            // 0..511
            const int krow = c >> 3;                 // 0..63
            const int scb = ((c & 7) * 16) ^ ((krow & 7) << 4);
            int g = kbeg + krow; if (g > 391) g = 391;   // clamp into batch pad (masked)
            const short* gk = kbase + (size_t)g * 1536 + (scb >> 1);
            __builtin_amdgcn_global_load_lds((gas_ptr)gk, (las_ptr)((char*)&klds[buf][0] + c * 16), 16, 0, 0);
        }
        #pragma unroll
        for (int it = 0; it < 2; ++it) {
            const int c = it * 256 + tid;
            const int vrow = c >> 3;                 // d 0..63
            const int scb = ((c & 7) * 16) ^ ((vrow & 7) << 4);
            const short* gv = vbase + (size_t)vrow * 392 + kbeg + (scb >> 1);  // over-read finite, P==0
            __builtin_amdgcn_global_load_lds((gas_ptr)gv, (las_ptr)((char*)&vlds[buf][0] + c * 16), 16, 0, 0);
        }
    };

    stage64(0, 0);

    for (int ch = 0; ch < nch; ++ch) {
        const int cur = ch & 1;
        if (ch + 1 < nch) {
            stage64(ch + 1, cur ^ 1);                      // next chunk under compute
            asm volatile("s_waitcnt vmcnt(4)" ::: "memory");   // chunk ch landed
        } else {
            asm volatile("s_waitcnt vmcnt(0)" ::: "memory");
        }
        __builtin_amdgcn_s_barrier();
        __builtin_amdgcn_sched_barrier(0);

        attn_chunk64(ch * 64, k_len, &klds[cur][0], &vlds[cur][0],
                     qf, my, lrow, lgrp, rs, oacc);

        __builtin_amdgcn_sched_barrier(0);
        __builtin_amdgcn_s_barrier();   // all reads done before next stage overwrites
    }

    // row-sum lives per-lane for q = lane&15: reduce over the 4 lane-groups
    rs += __shfl_xor(rs, 16, 64);
    rs += __shfl_xor(rs, 32, 64);

    // redistribute: output rows are q = lgrp*4 + r; lanes 0..15 hold rs[q=lane]
    float inv[4];
    #pragma unroll
    for (int r = 0; r < 4; ++r) inv[r] = 1.0f / __shfl(rs, lgrp * 4 + r, 64);

    #pragma unroll
    for (int r = 0; r < 4; ++r) {
        const int qn = q0 + lgrp * 4 + r;
        if (qn < qend) {
            #pragma unroll
            for (int dt = 0; dt < 4; ++dt)
                ao[((size_t)b * 388 + qn) * 768 + h * 64 + dt * 16 + lrow] =
                    f2bf(oacc[dt][r] * inv[r]);
        }
    }
}

extern "C" void kernel_launch(void* const* d_in, const int* in_sizes, int n_in,
                              void* d_out, int out_size, void* d_ws, size_t ws_size,
                              hipStream_t stream) {
    (void)in_sizes; (void)n_in; (void)out_size; (void)ws_size;
    const float* x      = (const float*)d_in[0];
    const float* qkv_w  = (const float*)d_in[1];
    const float* qkv_b  = (const float*)d_in[2];
    const float* proj_w = (const float*)d_in[3];
    const float* proj_b = (const float*)d_in[4];
    float* out = (float*)d_out;

    char* ws = (char*)d_ws;
    short* xb   = (short*)(ws);                       // [25088][768] bf16 (padded x)
    short* attn = (short*)(ws);                       //   alias: xb dead after QKV GEMM
    short* qkb  = (short*)(ws + 38535168);            // [25088][1536] bf16 (q|k)
    short* vTb  = (short*)(ws + 115605504);           // [768][64][392] bf16
    short* qwb  = (short*)(ws + 154140672);           // 2304x768 bf16 (V tail over-reads land here)
    short* pwb  = (short*)(ws + 157679616);           // 768x768 bf16

    cvt_all<<<2048, 256, 0, stream>>>(x, qkv_w, proj_w, xb, qwb, pwb);

    // QKV GEMM: M'=25088 (196x128), N=2304 (18x128), A-in-registers engine
    gemm_qkv_areg<<<dim3(196 * 18), 256, 0, stream>>>(xb, qwb, qkv_b, qkb, vTb);

    attn_flash<<<dim3(5376), 256, 0, stream>>>(qkb, vTb, attn);

    // proj GEMM: M=24832 (194x128), N=768 (6x128)
    gemm_proj<<<dim3(194 * 6), 256, 0, stream>>>(attn, pwb, proj_b, out, 6);
}

// Round 19
// 218.928 us; speedup vs baseline: 1.1859x; 1.1859x over previous
//
#include <hip/hip_runtime.h>
#include <cstdint>
#include <cstddef>
#include <cmath>

typedef __attribute__((ext_vector_type(4))) float f32x4;
typedef __attribute__((ext_vector_type(8))) short bf16x8;

typedef const __attribute__((address_space(1))) void* gas_ptr;
typedef __attribute__((address_space(3))) void* las_ptr;

// compiler-native bf16 convert (RNE) -> v_cvt_pk_bf16_f32 path
static __device__ __forceinline__ short f2bf(float f) {
    __bf16 h = (__bf16)f;
    return __builtin_bit_cast(short, h);
}

constexpr int MP = 25088;   // 64 * 392 batch-padded rows

// ---------------- merged fp32 -> bf16 conversion (one launch) ----------------
__global__ void cvt_all(const float* __restrict__ x,  const float* __restrict__ qw,
                        const float* __restrict__ pw,
                        short* __restrict__ xb, short* __restrict__ qwb,
                        short* __restrict__ pwb)
{
    constexpr int NX = MP * 768 / 4;
    constexpr int NQ = 2304 * 768 / 4;
    constexpr int NP = 768 * 768 / 4;
    constexpr int NT = NX + NQ + NP;
    int i = blockIdx.x * blockDim.x + threadIdx.x;
    const int stride = gridDim.x * blockDim.x;
    for (; i < NT; i += stride) {
        if (i < NX) {
            const int flat = i * 4;
            const int mp  = flat / 768;
            const int col = flat - mp * 768;
            const int b   = mp / 392;
            const int nn  = mp - b * 392;
            short4 o;
            if (nn < 388) {
                const float4 v = *reinterpret_cast<const float4*>(
                    x + ((size_t)(b * 388 + nn) * 768 + col));
                o.x = f2bf(v.x); o.y = f2bf(v.y); o.z = f2bf(v.z); o.w = f2bf(v.w);
            } else {
                o.x = 0; o.y = 0; o.z = 0; o.w = 0;
            }
            reinterpret_cast<short4*>(xb)[i] = o;
        } else if (i < NX + NQ) {
            const int j = i - NX;
            const float4 v = reinterpret_cast<const float4*>(qw)[j];
            short4 o;
            o.x = f2bf(v.x); o.y = f2bf(v.y); o.z = f2bf(v.z); o.w = f2bf(v.w);
            reinterpret_cast<short4*>(qwb)[j] = o;
        } else {
            const int j = i - NX - NQ;
            const float4 v = reinterpret_cast<const float4*>(pw)[j];
            short4 o;
            o.x = f2bf(v.x); o.y = f2bf(v.y); o.z = f2bf(v.z); o.w = f2bf(v.w);
            reinterpret_cast<short4*>(pwb)[j] = o;
        }
    }
}

// ---------------- bf16 GEMM  C = A (MxK) * B^T (NxK), K=768 ----------------
// r9-proven engine: 128x128 tile, BK=64, 4 waves, 64KB dbuf LDS (2 blocks/CU),
// counted-vmcnt pipeline (stage(kt+1); vmcnt(8); barrier; compute; barrier),
// XCD-bijective 1D swizzle. MODE 0 (QKV): supertiled wgid order (G=14) for L2;
// q cols pre-scaled 0.125*log2e; v -> in-LDS 64x64 transpose -> coalesced vT.
// MODE 1 (proj): plain order, fp32 out + bias.
template<int MODE>
__global__ __launch_bounds__(256) void gemm_bt(
    const short* __restrict__ A, const short* __restrict__ Bw,
    const float* __restrict__ bias,
    short* __restrict__ qk, short* __restrict__ vT,
    float* __restrict__ fo, int NB)
{
    constexpr int K = 768;
    constexpr int KT = 12;
    __shared__ __align__(16) short ldsraw[2 * 128 * 64 * 2];
    short* ldsA = ldsraw;
    short* ldsB = ldsraw + 2 * 128 * 64;

    const int tid  = threadIdx.x;
    const int lane = tid & 63;
    const int wid  = tid >> 6;
    const int lrow = lane & 15;
    const int lgrp = lane >> 4;
    const int wr   = wid >> 1;
    const int wc   = wid & 1;

    const int nwg = gridDim.x;
    const int q8  = nwg >> 3, r8 = nwg & 7;
    const int xcd = blockIdx.x & 7, bidx = blockIdx.x >> 3;
    const int wgid = (xcd < r8 ? xcd * (q8 + 1) : r8 * (q8 + 1) + (xcd - r8) * q8) + bidx;

    int m0, n0;
    if constexpr (MODE == 0) {
        constexpr int G = 14, SG = G * 18;
        const int mg = wgid / SG;
        const int r  = wgid - mg * SG;
        const int n  = r / G;
        const int mi = r - n * G;
        m0 = (mg * G + mi) * 128;
        n0 = n * 128;
    } else {
        m0 = (wgid / NB) * 128;
        n0 = (wgid % NB) * 128;
    }

    f32x4 acc[4][4];
    #pragma unroll
    for (int i = 0; i < 4; ++i)
        #pragma unroll
        for (int j = 0; j < 4; ++j)
            acc[i][j] = f32x4{0.f, 0.f, 0.f, 0.f};

    auto stage = [&](int kt, int buf) {
        #pragma unroll
        for (int it = 0; it < 4; ++it) {
            const int c   = it * 256 + wid * 64 + lane;
            const int row = c >> 3;
            const int scb = ((c & 7) * 16) ^ ((row & 7) << 4);
            const short* ga = A  + (size_t)(m0 + row) * K + kt * 64 + (scb >> 1);
            const short* gb = Bw + (size_t)(n0 + row) * K + kt * 64 + (scb >> 1);
            __builtin_amdgcn_global_load_lds((gas_ptr)ga, (las_ptr)((char*)(ldsA + buf * 128 * 64) + c * 16), 16, 0, 0);
            __builtin_amdgcn_global_load_lds((gas_ptr)gb, (las_ptr)((char*)(ldsB + buf * 128 * 64) + c * 16), 16, 0, 0);
        }
    };

    stage(0, 0);

    for (int kt = 0; kt < KT; ++kt) {
        const int cur = kt & 1;
        if (kt + 1 < KT) {
            stage(kt + 1, cur ^ 1);
            asm volatile("s_waitcnt vmcnt(8)" ::: "memory");
        } else {
            asm volatile("s_waitcnt vmcnt(0)" ::: "memory");
        }
        __builtin_amdgcn_s_barrier();
        __builtin_amdgcn_sched_barrier(0);

        #pragma unroll
        for (int ks = 0; ks < 2; ++ks) {
            bf16x8 af[4], bfv[4];
            #pragma unroll
            for (int i = 0; i < 4; ++i) {
                const int r   = wr * 64 + i * 16 + lrow;
                const int byt = r * 128 + ((ks * 64 + lgrp * 16) ^ ((r & 7) << 4));
                af[i] = *reinterpret_cast<const bf16x8*>((const char*)(ldsA + cur * 128 * 64) + byt);
            }
            #pragma unroll
            for (int j = 0; j < 4; ++j) {
                const int r   = wc * 64 + j * 16 + lrow;
                const int byt = r * 128 + ((ks * 64 + lgrp * 16) ^ ((r & 7) << 4));
                bfv[j] = *reinterpret_cast<const bf16x8*>((const char*)(ldsB + cur * 128 * 64) + byt);
            }
            #pragma unroll
            for (int i = 0; i < 4; ++i)
                #pragma unroll
                for (int j = 0; j < 4; ++j)
                    acc[i][j] = __builtin_amdgcn_mfma_f32_16x16x32_bf16(af[i], bfv[j], acc[i][j], 0, 0, 0);
        }

        __builtin_amdgcn_sched_barrier(0);
        __builtin_amdgcn_s_barrier();
    }

    const int mb = m0 + wr * 64;
    const int nb = n0 + wc * 64;
    if constexpr (MODE == 0) {
        if (n0 < 1536) {
            #pragma unroll
            for (int j = 0; j < 4; ++j) {
                const int c  = nb + j * 16 + lrow;
                const float sc = (c < 768) ? 0.18033688011116f : 1.0f;  // 0.125*log2(e) on q
                const float bv = bias[c];
                #pragma unroll
                for (int i = 0; i < 4; ++i) {
                    #pragma unroll
                    for (int r = 0; r < 4; ++r) {
                        const int m = mb + i * 16 + lgrp * 4 + r;
                        qk[(size_t)m * 1536 + c] = f2bf((acc[i][j][r] + bv) * sc);
                    }
                }
            }
        } else {
            const int h = (nb - 1536) >> 6;
            short* lw = ldsraw + wid * (64 * 80);
            #pragma unroll
            for (int j = 0; j < 4; ++j) {
                const int dloc = j * 16 + lrow;
                const float bv = bias[nb + j * 16 + lrow];
                #pragma unroll
                for (int i = 0; i < 4; ++i)
                    #pragma unroll
                    for (int r = 0; r < 4; ++r)
                        lw[dloc * 80 + i * 16 + lgrp * 4 + r] = f2bf(acc[i][j][r] + bv);
            }
            asm volatile("s_waitcnt lgkmcnt(0)" ::: "memory");
            __builtin_amdgcn_sched_barrier(0);
            #pragma unroll
            for (int w = 0; w < 8; ++w) {
                const int d    = w * 8 + (lane >> 3);
                const int nloc = (lane & 7) * 8;
                const bf16x8 val = *reinterpret_cast<const bf16x8*>(lw + d * 80 + nloc);
                const int mchunk = mb + nloc;
                const int b  = mchunk / 392;
                const int nn = mchunk - b * 392;
                short* dst = vT + ((size_t)(b * 12 + h) * 64 + d) * 392 + nn;
                *reinterpret_cast<bf16x8*>(dst) = val;
            }
        }
    } else {
        #pragma unroll
        for (int i = 0; i < 4; ++i) {
            #pragma unroll
            for (int r = 0; r < 4; ++r) {
                const int m = mb + i * 16 + lgrp * 4 + r;
                #pragma unroll
                for (int j = 0; j < 4; ++j) {
                    const int c = nb + j * 16 + lrow;
                    fo[(size_t)m * 768 + c] = acc[i][j][r] + bias[c];
                }
            }
        }
    }
}

// ---------------- flash attention: KVBLK=64, swapped-QK softmax ------------
// Swapped QK^T: sacc = mfma(K_frag, Q_frag) so C col = q (lane&15) and
// C row = key (lgrp*4+r within 16-block). Each lane owns 16 S-values of ONE
// q-row -> P-writes pack 4 consecutive keys per ds_write_b64, row-sum is a
// per-lane scalar (2 shfl_xor at the end). PV path & layouts unchanged.
constexpr int PSTRB = 128;   // P row stride BYTES (64 keys)

static __device__ __forceinline__ void attn_chunk64(
    int kbeg, int k_len,
    const short* __restrict__ klds, const short* __restrict__ vlds,
    const bf16x8 (&qf)[2], char* __restrict__ my,
    int lrow, int lgrp,
    float& rs, f32x4 (&oacc)[4])
{
    f32x4 sacc[4];
    #pragma unroll
    for (int t = 0; t < 4; ++t) sacc[t] = f32x4{0.f, 0.f, 0.f, 0.f};

    #pragma unroll
    for (int t = 0; t < 4; ++t) {
        const int kl   = t * 16 + lrow;
        const int byt0 = kl * 128 + ((lgrp * 16) ^ ((kl & 7) << 4));
        const int byt1 = kl * 128 + ((64 + lgrp * 16) ^ ((kl & 7) << 4));
        const bf16x8 k0 = *reinterpret_cast<const bf16x8*>((const char*)klds + byt0);
        const bf16x8 k1 = *reinterpret_cast<const bf16x8*>((const char*)klds + byt1);
        // SWAPPED: A = K rows (keys), B = Q rows (q)
        sacc[t] = __builtin_amdgcn_mfma_f32_16x16x32_bf16(k0, qf[0], sacc[t], 0, 0, 0);
        sacc[t] = __builtin_amdgcn_mfma_f32_16x16x32_bf16(k1, qf[1], sacc[t], 0, 0, 0);
    }

    // exp2, pack 4 keys per b64 write, per-lane scalar row-sum
    if (kbeg + 64 <= k_len) {          // uniform fast path: no key masking
        #pragma unroll
        for (int t = 0; t < 4; ++t) {
            short4 pk;
            #pragma unroll
            for (int r = 0; r < 4; ++r) {
                const float p = exp2f(sacc[t][r]);
                rs += p;
                ((short*)&pk)[r] = f2bf(p);
            }
            const int byt = lrow * PSTRB + ((t * 32 + lgrp * 8) ^ ((lrow & 7) << 4));
            *reinterpret_cast<short4*>(my + byt) = pk;
        }
    } else {
        #pragma unroll
        for (int t = 0; t < 4; ++t) {
            short4 pk;
            #pragma unroll
            for (int r = 0; r < 4; ++r) {
                const int key = kbeg + t * 16 + lgrp * 4 + r;   // row-indexed
                const float p = (key < k_len) ? exp2f(sacc[t][r]) : 0.f;
                rs += p;
                ((short*)&pk)[r] = f2bf(p);
            }
            const int byt = lrow * PSTRB + ((t * 32 + lgrp * 8) ^ ((lrow & 7) << 4));
            *reinterpret_cast<short4*>(my + byt) = pk;
        }
    }

    #pragma unroll
    for (int ks = 0; ks < 2; ++ks) {
        const bf16x8 pf = *reinterpret_cast<const bf16x8*>(
            my + lrow * PSTRB + ((ks * 64 + lgrp * 16) ^ ((lrow & 7) << 4)));
        #pragma unroll
        for (int dt = 0; dt < 4; ++dt) {
            const int d = dt * 16 + lrow;
            const bf16x8 vf = *reinterpret_cast<const bf16x8*>(
                (const char*)vlds + d * 128 + ((ks * 64 + lgrp * 16) ^ ((d & 7) << 4)));
            oacc[dt] = __builtin_amdgcn_mfma_f32_16x16x32_bf16(pf, vf, oacc[dt], 0, 0, 0);
        }
    }
}

// grid 5376 1-D; temporal-L2 map: 7 q-tiles of one bh consecutive on one XCD.
__global__ __launch_bounds__(256, 4) void attn_flash(
    const short* __restrict__ qkb, const short* __restrict__ vT,
    short* __restrict__ ao)
{
    __shared__ __align__(16) short klds[2][64 * 64];    // 16KB dbuf, swizzled
    __shared__ __align__(16) short vlds[2][64 * 64];    // 16KB dbuf, swizzled
    __shared__ __align__(16) char  plds[4][16 * PSTRB]; // 8KB, swizzled

    const int tid  = threadIdx.x;
    const int lane = tid & 63;
    const int wid  = tid >> 6;
    const int lrow = lane & 15;
    const int lgrp = lane >> 4;

    const int blk = blockIdx.x;
    const int xcd = blk & 7;
    const int i7  = blk >> 3;
    const int bh  = xcd * 96 + i7 / 7;
    const int bx  = i7 % 7;

    int q_start, qend, k_len, nch;
    if (bx < 2) { q_start = bx * 64;             qend = 128; k_len = 128; nch = 2; }
    else        { q_start = 128 + (bx - 2) * 64; qend = 388; k_len = 388; nch = 7; }

    const int q0 = q_start + wid * 16;

    const int b = bh / 12, h = bh - b * 12;
    const short* qbase = qkb + (size_t)b * 392 * 1536 + h * 64;
    const short* kbase = qbase + 768;
    const short* vbase = vT + (size_t)bh * 64 * 392;

    int qrow = q0 + lrow; if (qrow >= qend) qrow = qend - 1;
    bf16x8 qf[2];
    #pragma unroll
    for (int ks = 0; ks < 2; ++ks)
        qf[ks] = *reinterpret_cast<const bf16x8*>(qbase + (size_t)qrow * 1536 + ks * 32 + lgrp * 8);

    float rs = 0.f;
    f32x4 oacc[4];
    #pragma unroll
    for (int dt = 0; dt < 4; ++dt) oacc[dt] = f32x4{0.f, 0.f, 0.f, 0.f};

    char* my = &plds[wid][0];

    // stage one 64-key chunk: K [64][64] + V [64][64], 4 DMAs/thread.
    auto stage64 = [&](int ch, int buf) {
        const int kbeg = ch * 64;
        #pragma unroll
        for (int it = 0; it < 2; ++it) {
            const int c = it * 256 + tid;            // 0..511
            const int krow = c >> 3;                 // 0..63
            const int scb = ((c & 7) * 16) ^ ((krow & 7) << 4);
            int g = kbeg + krow; if (g > 391) g = 391;   // clamp into batch pad (masked)
            const short* gk = kbase + (size_t)g * 1536 + (scb >> 1);
            __builtin_amdgcn_global_load_lds((gas_ptr)gk, (las_ptr)((char*)&klds[buf][0] + c * 16), 16, 0, 0);
        }
        #pragma unroll
        for (int it = 0; it < 2; ++it) {
            const int c = it * 256 + tid;
            const int vrow = c >> 3;                 // d 0..63
            const int scb = ((c & 7) * 16) ^ ((vrow & 7) << 4);
            const short* gv = vbase + (size_t)vrow * 392 + kbeg + (scb >> 1);  // over-read finite, P==0
            __builtin_amdgcn_global_load_lds((gas_ptr)gv, (las_ptr)((char*)&vlds[buf][0] + c * 16), 16, 0, 0);
        }
    };

    stage64(0, 0);

    for (int ch = 0; ch < nch; ++ch) {
        const int cur = ch & 1;
        if (ch + 1 < nch) {
            stage64(ch + 1, cur ^ 1);                      // next chunk under compute
            asm volatile("s_waitcnt vmcnt(4)" ::: "memory");   // chunk ch landed
        } else {
            asm volatile("s_waitcnt vmcnt(0)" ::: "memory");
        }
        __builtin_amdgcn_s_barrier();
        __builtin_amdgcn_sched_barrier(0);

        attn_chunk64(ch * 64, k_len, &klds[cur][0], &vlds[cur][0],
                     qf, my, lrow, lgrp, rs, oacc);

        __builtin_amdgcn_sched_barrier(0);
        __builtin_amdgcn_s_barrier();   // all reads done before next stage overwrites
    }

    // row-sum lives per-lane for q = lane&15: reduce over the 4 lane-groups
    rs += __shfl_xor(rs, 16, 64);
    rs += __shfl_xor(rs, 32, 64);

    // redistribute: output rows are q = lgrp*4 + r; lanes 0..15 hold rs[q=lane]
    float inv[4];
    #pragma unroll
    for (int r = 0; r < 4; ++r) inv[r] = 1.0f / __shfl(rs, lgrp * 4 + r, 64);

    #pragma unroll
    for (int r = 0; r < 4; ++r) {
        const int qn = q0 + lgrp * 4 + r;
        if (qn < qend) {
            #pragma unroll
            for (int dt = 0; dt < 4; ++dt)
                ao[((size_t)b * 388 + qn) * 768 + h * 64 + dt * 16 + lrow] =
                    f2bf(oacc[dt][r] * inv[r]);
        }
    }
}

extern "C" void kernel_launch(void* const* d_in, const int* in_sizes, int n_in,
                              void* d_out, int out_size, void* d_ws, size_t ws_size,
                              hipStream_t stream) {
    (void)in_sizes; (void)n_in; (void)out_size; (void)ws_size;
    const float* x      = (const float*)d_in[0];
    const float* qkv_w  = (const float*)d_in[1];
    const float* qkv_b  = (const float*)d_in[2];
    const float* proj_w = (const float*)d_in[3];
    const float* proj_b = (const float*)d_in[4];
    float* out = (float*)d_out;

    char* ws = (char*)d_ws;
    short* xb   = (short*)(ws);                       // [25088][768] bf16 (padded x)
    short* attn = (short*)(ws);                       //   alias: xb dead after QKV GEMM
    short* qkb  = (short*)(ws + 38535168);            // [25088][1536] bf16 (q|k)
    short* vTb  = (short*)(ws + 115605504);           // [768][64][392] bf16
    short* qwb  = (short*)(ws + 154140672);           // 2304x768 bf16 (V tail over-reads land here)
    short* pwb  = (short*)(ws + 157679616);           // 768x768 bf16

    cvt_all<<<2048, 256, 0, stream>>>(x, qkv_w, proj_w, xb, qwb, pwb);

    // QKV GEMM: M'=25088 (196x128), N=2304 (18x128), supertiled order
    gemm_bt<0><<<dim3(196 * 18), 256, 0, stream>>>(xb, qwb, qkv_b, qkb, vTb, nullptr, 18);

    attn_flash<<<dim3(5376), 256, 0, stream>>>(qkb, vTb, attn);

    // proj GEMM: M=24832 (194x128), N=768 (6x128)
    gemm_bt<1><<<dim3(194 * 6), 256, 0, stream>>>(attn, pwb, proj_b, nullptr, nullptr, out, 6);
}